// Round 5
// baseline (315.635 us; speedup 1.0000x reference)
//
#include <hip/hip_runtime.h>
#include <math.h>

#define HDIM 60
#define EPSC 0.01f
#define ALPHAC 0.1f

// ---------------------------------------------------------------------------
// Kernel 1: compute h_0 = ICNN(Xref) once into workspace (single tiny block).
// ---------------------------------------------------------------------------
__global__ void dho_h0_kernel(const float* __restrict__ Xref,
                              const float* __restrict__ W1, const float* __restrict__ b1,
                              const float* __restrict__ W2, const float* __restrict__ b2,
                              const float* __restrict__ W3, const float* __restrict__ b3,
                              const float* __restrict__ Wim2, const float* __restrict__ Wim3,
                              float* __restrict__ h0out)
{
    __shared__ float z1s[HDIM];
    __shared__ float z2s[HDIM];
    const int t = threadIdx.x;
    const float x0 = Xref[0], x1 = Xref[1];
    if (t < HDIM) {
        float a = W1[2 * t] * x0 + W1[2 * t + 1] * x1 + b1[t];
        float e = expf(-fabsf(a));
        z1s[t] = logf(1.0f + e) + fmaxf(a, 0.0f);
    }
    __syncthreads();
    if (t < HDIM) {
        float a = b2[t] + Wim2[2 * t] * x0 + Wim2[2 * t + 1] * x1;
        for (int i = 0; i < HDIM; ++i) a += W2[t * HDIM + i] * z1s[i];
        float e = expf(-fabsf(a));
        z2s[t] = logf(1.0f + e) + fmaxf(a, 0.0f);
    }
    __syncthreads();
    if (t == 0) {
        float a = b3[0] + Wim3[0] * x0 + Wim3[1] * x1;
        for (int j = 0; j < HDIM; ++j) a += W3[j] * z2s[j];
        float e = expf(-fabsf(a));
        h0out[0] = logf(1.0f + e) + fmaxf(a, 0.0f);
    }
}

// ---------------------------------------------------------------------------
// Kernel 2: identical to R4 EXCEPT __launch_bounds__(256, 1).
// R4 evidence: with (256,2) the allocator capped arch VGPRs at 128 and put
// z1/g1/row into AGPRs -> every array access pays v_accvgpr_read/write
// (measured ~25k instr/sample vs ~10k floor). (256,1) lifts the cap to the
// full 512-reg unified budget; peak live ~200 floats fits in arch VGPRs.
// Occupancy is 2 waves/SIMD for any VGPR count in (128,256] -> no cost.
// ---------------------------------------------------------------------------
__global__ __launch_bounds__(256, 1) void dho_main_kernel(
    const float* __restrict__ X, const float* __restrict__ U,
    const float* __restrict__ W1, const float* __restrict__ b1,
    const float* __restrict__ W2, const float* __restrict__ b2,
    const float* __restrict__ W3,
    const float* __restrict__ Wim2,
    const float* __restrict__ W_fnn, const float* __restrict__ W_gnn,
    const float* __restrict__ b_gnn, const float* __restrict__ b3,
    const float* __restrict__ Wim3, const float* __restrict__ Xref,
    const float* __restrict__ h0p,
    float* __restrict__ out, int N)
{
    __shared__ __align__(16) float sW2[HDIM * HDIM];   // 14400 B, row-major
    __shared__ float4 sW1b[HDIM];                      // (W1[i,0], W1[i,1], b1[i], 0)
    __shared__ float4 sJ[HDIM];                        // (b2[j], Wim2[j,0], Wim2[j,1], W3[j])

    const int t = threadIdx.x;
    for (int k = t; k < HDIM * HDIM; k += 256) sW2[k] = W2[k];
    if (t < HDIM) {
        sW1b[t] = make_float4(W1[2 * t], W1[2 * t + 1], b1[t], 0.0f);
        sJ[t]   = make_float4(b2[t], Wim2[2 * t], Wim2[2 * t + 1], W3[t]);
    }
    __syncthreads();

    const int n_raw = blockIdx.x * 256 + t;
    const int n = n_raw < N ? n_raw : N - 1;    // clamp: uniform control flow

    const float2 x = ((const float2*)X)[n];
    const float  u = U[n];

    // ---- layer 1: z1 = softplus(W1 x + b1) ----
    float z1[HDIM];
#pragma unroll
    for (int i = 0; i < HDIM; ++i) {
        float4 w = sW1b[i];
        float a  = w.x * x.x + w.y * x.y + w.z;
        float e  = __expf(-fabsf(a));
        z1[i] = __logf(1.0f + e) + fmaxf(a, 0.0f);
    }

    // ---- layer 2 fwd + reverse-mode accumulation, one LDS row load per j ----
    float g1[HDIM];
#pragma unroll
    for (int i = 0; i < HDIM; ++i) g1[i] = 0.0f;

    float a3acc = 0.0f, q0 = 0.0f, q1 = 0.0f;

#pragma unroll 1
    for (int j = 0; j < HDIM; ++j) {
        const float4* rp = (const float4*)(&sW2[j * HDIM]);
        float4 r[15];
#pragma unroll
        for (int c = 0; c < 15; ++c) r[c] = rp[c];      // ds_read_b128 x15, broadcast
        float4 pj = sJ[j];                              // b2, wi0, wi1, w3

        float acc0 = 0.0f, acc1 = 0.0f, acc2 = 0.0f, acc3 = 0.0f;
#pragma unroll
        for (int c = 0; c < 15; ++c) {
            acc0 += r[c].x * z1[4 * c + 0];
            acc1 += r[c].y * z1[4 * c + 1];
            acc2 += r[c].z * z1[4 * c + 2];
            acc3 += r[c].w * z1[4 * c + 3];
        }
        float a2 = (acc0 + acc1) + (acc2 + acc3) + pj.x + pj.y * x.x + pj.z * x.y;

        float e   = __expf(-fabsf(a2));
        float inv = __builtin_amdgcn_rcpf(1.0f + e);
        float z2  = __logf(1.0f + e) + fmaxf(a2, 0.0f);
        float s2  = (a2 >= 0.0f ? 1.0f : e) * inv;

        a3acc += pj.w * z2;
        float tj = pj.w * s2;
        q0 += tj * pj.y;
        q1 += tj * pj.z;
#pragma unroll
        for (int c = 0; c < 15; ++c) {
            g1[4 * c + 0] += tj * r[c].x;
            g1[4 * c + 1] += tj * r[c].y;
            g1[4 * c + 2] += tj * r[c].z;
            g1[4 * c + 3] += tj * r[c].w;
        }
    }

    // ---- output layer ----
    const float wim3_0 = Wim3[0], wim3_1 = Wim3[1];
    float a3   = a3acc + b3[0] + wim3_0 * x.x + wim3_1 * x.y;
    float e3   = __expf(-fabsf(a3));
    float inv3 = __builtin_amdgcn_rcpf(1.0f + e3);
    float hX   = __logf(1.0f + e3) + fmaxf(a3, 0.0f);
    float s3   = (a3 >= 0.0f ? 1.0f : e3) * inv3;

    float h = hX - h0p[0];
    float sigma, sigp;
    if (h >= 1.0f)      { sigma = h - 0.5f;     sigp = 1.0f; }
    else if (h > 0.0f)  { sigma = 0.5f * h * h; sigp = h;    }
    else                { sigma = 0.0f;         sigp = 0.0f; }

    float dx0 = x.x - Xref[0], dx1 = x.y - Xref[1];
    float V = sigma + EPSC * (dx0 * dx0 + dx1 * dx1);

    // ---- backprop through layer 1 ----
    float sum0 = 0.0f, sum1 = 0.0f;
#pragma unroll
    for (int i = 0; i < HDIM; ++i) {
        float4 w  = sW1b[i];
        float s1v = 1.0f - __expf(-z1[i]);   // sigmoid(a1) = 1 - exp(-softplus(a1))
        float c   = g1[i] * s1v;
        sum0 += c * w.x;
        sum1 += c * w.y;
    }
    float dh0 = s3 * (wim3_0 + q0 + sum0);
    float dh1 = s3 * (wim3_1 + q1 + sum1);

    float dV0 = sigp * dh0 + 2.0f * EPSC * dx0;
    float dV1 = sigp * dh1 + 2.0f * EPSC * dx1;

    // ---- dynamics + correction ----
    float f0  = W_fnn[0] * x.x + W_fnn[1] * x.y;
    float f1  = W_fnn[2] * x.x + W_fnn[3] * x.y;
    float gg0 = W_gnn[0] * x.x + W_gnn[1] * x.y + b_gnn[0];
    float gg1 = W_gnn[2] * x.x + W_gnn[3] * x.y + b_gnn[1];

    float sc  = dV0 * f0 + dV1 * f1 + ALPHAC * V - fabsf(dV0 * gg0 + dV1 * gg1);
    float nrm = dV0 * dV0 + dV1 * dV1;
    float rr  = fmaxf(sc, 0.0f) * __builtin_amdgcn_rcpf(nrm);

    float o0 = f0 - dV0 * rr + gg0 * u;
    float o1 = f1 - dV1 * rr + gg1 * u;
    if (n_raw < N) ((float2*)out)[n] = make_float2(o0, o1);
}

extern "C" void kernel_launch(void* const* d_in, const int* in_sizes, int n_in,
                              void* d_out, int out_size, void* d_ws, size_t ws_size,
                              hipStream_t stream) {
    // 0:X 1:U 2:Xref 3:W_fnn 4:W_gnn 5:b_gnn 6:W1 7:b1 8:W2 9:b2 10:W3 11:b3 12:Wim2 13:Wim3
    const float* X     = (const float*)d_in[0];
    const float* U     = (const float*)d_in[1];
    const float* Xref  = (const float*)d_in[2];
    const float* W_fnn = (const float*)d_in[3];
    const float* W_gnn = (const float*)d_in[4];
    const float* b_gnn = (const float*)d_in[5];
    const float* W1    = (const float*)d_in[6];
    const float* b1    = (const float*)d_in[7];
    const float* W2    = (const float*)d_in[8];
    const float* b2    = (const float*)d_in[9];
    const float* W3    = (const float*)d_in[10];
    const float* b3    = (const float*)d_in[11];
    const float* Wim2  = (const float*)d_in[12];
    const float* Wim3  = (const float*)d_in[13];

    const int N = in_sizes[0] / 2;
    float* h0  = (float*)d_ws;
    float* out = (float*)d_out;

    dho_h0_kernel<<<1, 64, 0, stream>>>(Xref, W1, b1, W2, b2, W3, b3, Wim2, Wim3, h0);

    const int blocks = (N + 255) / 256;
    dho_main_kernel<<<blocks, 256, 0, stream>>>(
        X, U, W1, b1, W2, b2, W3, Wim2,
        W_fnn, W_gnn, b_gnn, b3, Wim3, Xref, h0,
        out, N);
}